// Round 10
// baseline (95.901 us; speedup 1.0000x reference)
//
#include <hip/hip_runtime.h>
#include <hip/hip_bf16.h>
#include <cstdint>

#define SS   2048
#define DD   128
#define KBLK 64
#define NKT  32                      // key tiles per batch
#define TILE_BYTES 16384             // 64 keys x 128 d bf16, frag-ordered

#define NBLK 640                     // CHUNK=8 chunks, QBLK=128
#define WS_K    ((size_t)0)
#define WS_V    ((size_t)16 * NKT * TILE_BYTES)             // 8 MB
#define WS_PO   ((size_t)16 * NKT * TILE_BYTES * 2)         // 16 MB
#define WS_ML   (WS_PO + (size_t)NBLK * 128 * 128 * 2)      // +20 MB
#define WS_NEED (WS_ML + (size_t)NBLK * 128 * 4)            // ~36.4 MB

typedef __attribute__((ext_vector_type(8)))  short short8;   // 8 bf16 (MFMA A/B)
typedef __attribute__((ext_vector_type(16))) float f32x16;   // 32x32 MFMA C/D
typedef __attribute__((ext_vector_type(4)))  float f32x4;

__device__ __forceinline__ unsigned short f2bf(float x) {
  return __builtin_bit_cast(unsigned short, (__bf16)x);
}
__device__ __forceinline__ float bfbits2f(unsigned int lo16shifted) {
  return __builtin_bit_cast(float, lo16shifted);
}

// ---- chunk tables: q-block i (128 rows) has 2i+2 tiles; chunks of <=8 ----
// nch_i = {1,1,1,1,2,2,2,2,3,3,3,3,4,4,4,4}, total 40 slots/batch
__device__ __constant__ unsigned char V10_I[40] = {
  0,1,2,3, 4,4,5,5,6,6,7,7, 8,8,8,9,9,9,10,10,10,11,11,11,
  12,12,12,12,13,13,13,13,14,14,14,14,15,15,15,15};
__device__ __constant__ unsigned char V10_BASE[16] = {0,1,2,3,4,6,8,10,12,15,18,21,24,28,32,36};
__device__ __constant__ unsigned char V10_NCH[16]  = {1,1,1,1,2,2,2,2,3,3,3,3,4,4,4,4};

// ---------------------------------------------------------------------------
// Pre-pass: FRAGMENT-ORDERED bf16 tiles (proven v8/v9 layout).
//   K tile entry e = g*512 + s*64 + lane, 16B = K[g*32+l31][s*16+h*8 ..]
//   V tile entry e = (dg*4+s4)*64 + lane, 16B = V^T[dg*32+l31][pi-slots]
// ---------------------------------------------------------------------------
__global__ __launch_bounds__(256) void prepack_kv10(
    const float* __restrict__ K, const float* __restrict__ V, char* __restrict__ ws)
{
  __shared__ float st[64][132];
  const int b = blockIdx.x, t = blockIdx.y;
  const int tid = threadIdx.x;
  const float* Kt = K + ((size_t)b * SS + t * KBLK) * DD;
  const float* Vt = V + ((size_t)b * SS + t * KBLK) * DD;
  char* Kd = ws + WS_K + ((size_t)(b * NKT + t)) * TILE_BYTES;
  char* Vd = ws + WS_V + ((size_t)(b * NKT + t)) * TILE_BYTES;

  #pragma unroll
  for (int u = 0; u < 4; ++u) {
    int row = u * 16 + (tid >> 4);
    int col = 8 * (tid & 15);
    const float4* sp = reinterpret_cast<const float4*>(Kt + (size_t)row * DD + col);
    float4 x = sp[0], y = sp[1];
    *reinterpret_cast<float4*>(&st[row][col])     = x;
    *reinterpret_cast<float4*>(&st[row][col + 4]) = y;
  }
  __syncthreads();
  #pragma unroll
  for (int u = 0; u < 4; ++u) {
    int e = u * 256 + tid;
    int g = e >> 9, s = (e >> 6) & 7, lane = e & 63;
    int h = lane >> 5, l31 = lane & 31;
    int key = g * 32 + l31;
    int d0 = s * 16 + h * 8;
    float4 x = *reinterpret_cast<const float4*>(&st[key][d0]);
    float4 y = *reinterpret_cast<const float4*>(&st[key][d0 + 4]);
    short8 w;
    w[0] = f2bf(x.x); w[1] = f2bf(x.y); w[2] = f2bf(x.z); w[3] = f2bf(x.w);
    w[4] = f2bf(y.x); w[5] = f2bf(y.y); w[6] = f2bf(y.z); w[7] = f2bf(y.w);
    *reinterpret_cast<short8*>(Kd + e * 16) = w;
  }
  __syncthreads();

  #pragma unroll
  for (int u = 0; u < 4; ++u) {
    int row = u * 16 + (tid >> 4);
    int col = 8 * (tid & 15);
    const float4* sp = reinterpret_cast<const float4*>(Vt + (size_t)row * DD + col);
    float4 x = sp[0], y = sp[1];
    *reinterpret_cast<float4*>(&st[row][col])     = x;
    *reinterpret_cast<float4*>(&st[row][col + 4]) = y;
  }
  __syncthreads();
  #pragma unroll
  for (int u = 0; u < 4; ++u) {
    int e = u * 256 + tid;
    int dg = e >> 8, s4 = (e >> 6) & 3, lane = e & 63;
    int h = lane >> 5, l31 = lane & 31;
    int d = dg * 32 + l31;
    int y8 = s4 * 2 + h;
    short8 w;
    #pragma unroll
    for (int j = 0; j < 8; ++j) {
      int a = ((y8 >> 2) << 5) | (((y8 >> 1) & 1) << 4) | ((j >> 2) << 3) | (j & 3) | ((y8 & 1) << 2);
      w[j] = f2bf(st[a][d]);
    }
    *reinterpret_cast<short8*>(Vd + e * 16) = w;
  }
}

// ---------------------------------------------------------------------------
// Main v10: T14 reg-staged LDS pipeline. Per tile: compute(t) from LDS while
// tile t+1's global loads (issued last iteration) are in flight; barrier;
// ds_write regs->LDS (vmcnt already satisfied -> no drain); issue t+2 loads;
// barrier. LDS layout = frag-ordered linear (conflict-free contiguous 1KB).
// ---------------------------------------------------------------------------
__global__ __launch_bounds__(256) void sdpa_v10(
    const float* __restrict__ Q, const char* __restrict__ ws,
    float* __restrict__ O, unsigned short* __restrict__ partO,
    float* __restrict__ partML)
{
  __shared__ __align__(16) char smem[32768];   // K frag 16KB | V frag 16KB

  const int y = blockIdx.x;
  const int b = y & 15;
  const int slot = y >> 4;
  const int i = V10_I[slot];
  const int c = slot - V10_BASE[i];
  const int nch = V10_NCH[i];
  const int tiles = 2 * i + 2;
  const int kvt0 = 8 * c;
  const int ntile = (tiles - kvt0 < 8) ? (tiles - kvt0) : 8;
  const bool dostore = (nch == 1);

  const int tid  = threadIdx.x;
  const int lane = tid & 63;
  const int wid  = tid >> 6;     // 0..3
  const int l31  = lane & 31;
  const int h    = lane >> 5;

  const float* Qb  = Q + (size_t)b * SS * DD;
  const char*  Kws = ws + WS_K + ((size_t)(b * NKT)) * TILE_BYTES;
  const char*  Vws = ws + WS_V + ((size_t)(b * NKT)) * TILE_BYTES;

  const float qscale = 0.08838834764831845f * 1.4426950408889634f; // 1/sqrt(128)*log2e
  const int qg = 128 * i + wid * 32 + l31;

  // ---- Q fragments (B-operand), scale folded ----
  short8 qf[8];
  {
    const float* qrow = Qb + (size_t)qg * DD;
    #pragma unroll
    for (int s = 0; s < 8; ++s) {
      const float4* p = reinterpret_cast<const float4*>(qrow + s * 16 + h * 8);
      float4 x = p[0], z = p[1];
      short8 w;
      w[0] = f2bf(x.x * qscale); w[1] = f2bf(x.y * qscale);
      w[2] = f2bf(x.z * qscale); w[3] = f2bf(x.w * qscale);
      w[4] = f2bf(z.x * qscale); w[5] = f2bf(z.y * qscale);
      w[6] = f2bf(z.z * qscale); w[7] = f2bf(z.w * qscale);
      qf[s] = w;
    }
  }

  // staging: wave 0,1 -> K halves; wave 2,3 -> V halves. 8KB/wave = rs[8].
  const char* gsrc = (wid < 2) ? (Kws + wid * 8192) : (Vws + (wid - 2) * 8192);
  char* ldst = (wid < 2) ? (smem + wid * 8192) : (smem + 16384 + (wid - 2) * 8192);

  uint4 rs[8];
  {
    const char* src = gsrc + (size_t)kvt0 * TILE_BYTES;
    #pragma unroll
    for (int j = 0; j < 8; ++j)
      rs[j] = *reinterpret_cast<const uint4*>(src + j * 1024 + lane * 16);
  }
  #pragma unroll
  for (int j = 0; j < 8; ++j)
    *reinterpret_cast<uint4*>(ldst + j * 1024 + lane * 16) = rs[j];
  __syncthreads();
  if (ntile > 1) {
    const char* src = gsrc + (size_t)(kvt0 + 1) * TILE_BYTES;
    #pragma unroll
    for (int j = 0; j < 8; ++j)
      rs[j] = *reinterpret_cast<const uint4*>(src + j * 1024 + lane * 16);
  }

  f32x16 o[4];
  #pragma unroll
  for (int dg = 0; dg < 4; ++dg)
    #pragma unroll
    for (int r = 0; r < 16; ++r) o[dg][r] = 0.f;
  float lsum = 0.f;

  for (int t = 0; t < ntile; ++t) {
    const int tt = kvt0 + t;
    const bool domask = tt >= 2 * i;

    short8 pf[4];
    float psum = 0.f;

    // ---- QK^T per 32-key group (frag-ordered LDS reads) ----
    #pragma unroll
    for (int g = 0; g < 2; ++g) {
      short8 kf[8];
      #pragma unroll
      for (int s = 0; s < 8; ++s)
        kf[s] = *reinterpret_cast<const short8*>(smem + g * 8192 + s * 1024 + lane * 16);

      f32x16 acc;
      #pragma unroll
      for (int r = 0; r < 16; ++r) acc[r] = 0.f;
      __builtin_amdgcn_s_setprio(1);
      #pragma unroll
      for (int s = 0; s < 8; ++s)
        acc = __builtin_amdgcn_mfma_f32_32x32x16_bf16(kf[s], qf[s], acc, 0, 0, 0);
      __builtin_amdgcn_s_setprio(0);

      if (domask) {
        const int kb = tt * 64 + g * 32 + 4 * h;
        #pragma unroll
        for (int r = 0; r < 16; ++r) {
          int keyg = kb + (r & 3) + 8 * (r >> 2);
          if (keyg > qg) acc[r] = -1e30f;
        }
      }

      float pg[16];
      #pragma unroll
      for (int r = 0; r < 16; ++r) pg[r] = exp2f(acc[r]);
      float s0 = ((pg[0]+pg[1])+(pg[2]+pg[3])) + ((pg[4]+pg[5])+(pg[6]+pg[7]));
      float s1 = ((pg[8]+pg[9])+(pg[10]+pg[11])) + ((pg[12]+pg[13])+(pg[14]+pg[15]));
      psum += s0 + s1;

      short8 w0, w1;
      #pragma unroll
      for (int j = 0; j < 8; ++j) { w0[j] = f2bf(pg[j]); w1[j] = f2bf(pg[8 + j]); }
      pf[2 * g]     = w0;
      pf[2 * g + 1] = w1;
    }
    lsum += psum;

    // ---- PV ----
    __builtin_amdgcn_s_setprio(1);
    #pragma unroll
    for (int dg = 0; dg < 4; ++dg) {
      short8 vf[4];
      #pragma unroll
      for (int s4 = 0; s4 < 4; ++s4)
        vf[s4] = *reinterpret_cast<const short8*>(smem + 16384 + (dg * 4 + s4) * 1024 + lane * 16);
      #pragma unroll
      for (int s4 = 0; s4 < 4; ++s4)
        o[dg] = __builtin_amdgcn_mfma_f32_32x32x16_bf16(vf[s4], pf[s4], o[dg], 0, 0, 0);
    }
    __builtin_amdgcn_s_setprio(0);

    __syncthreads();                 // all waves done READING this tile
    if (t + 1 < ntile) {
      // rs holds tile t+1 (loads issued a full tile ago -> vmcnt satisfied)
      #pragma unroll
      for (int j = 0; j < 8; ++j)
        *reinterpret_cast<uint4*>(ldst + j * 1024 + lane * 16) = rs[j];
      if (t + 2 < ntile) {           // issue tile t+2 loads (fly during next compute)
        const char* src = gsrc + (size_t)(kvt0 + t + 2) * TILE_BYTES;
        #pragma unroll
        for (int j = 0; j < 8; ++j)
          rs[j] = *reinterpret_cast<const uint4*>(src + j * 1024 + lane * 16);
      }
      __syncthreads();               // ds_writes visible before next reads
    }
  }

  // ---- epilogue ----
  lsum += __shfl_xor(lsum, 32);

  if (dostore) {
    float inv = 1.0f / lsum;
    float* Ob = O + (size_t)b * SS * DD + (size_t)qg * DD;
    #pragma unroll
    for (int dg = 0; dg < 4; ++dg)
      #pragma unroll
      for (int rq = 0; rq < 4; ++rq) {
        int d0 = dg * 32 + 8 * rq + 4 * h;
        float4 w;
        w.x = o[dg][4 * rq + 0] * inv;
        w.y = o[dg][4 * rq + 1] * inv;
        w.z = o[dg][4 * rq + 2] * inv;
        w.w = o[dg][4 * rq + 3] * inv;
        *reinterpret_cast<float4*>(Ob + d0) = w;
      }
  } else {
    unsigned short* po = partO + (size_t)y * (128 * 128) + (size_t)(wid * 32 + l31) * 128;
    #pragma unroll
    for (int dg = 0; dg < 4; ++dg)
      #pragma unroll
      for (int rq = 0; rq < 4; ++rq) {
        int d0 = dg * 32 + 8 * rq + 4 * h;
        ushort4 u;
        u.x = f2bf(o[dg][4 * rq + 0]);
        u.y = f2bf(o[dg][4 * rq + 1]);
        u.z = f2bf(o[dg][4 * rq + 2]);
        u.w = f2bf(o[dg][4 * rq + 3]);
        *reinterpret_cast<ushort4*>(po + d0) = u;
      }
    if (h == 0) partML[y * 128 + wid * 32 + l31] = lsum;
  }
}

// ---------------------------------------------------------------------------
// Merge for i>=4: O[b][128i+row][:] = (sum_c U_c) / (sum_c l_c)
// ---------------------------------------------------------------------------
__global__ __launch_bounds__(256) void merge_v10(
    const unsigned short* __restrict__ partO, const float* __restrict__ partML,
    float* __restrict__ O)
{
  const int b = blockIdx.x;
  const int i = blockIdx.y + 4;
  const int rg = blockIdx.z;
  const int tid = threadIdx.x;
  const int row = rg * 32 + (tid >> 3);
  const int c0  = (tid & 7) * 16;

  float acc[16];
  #pragma unroll
  for (int u = 0; u < 16; ++u) acc[u] = 0.f;
  float ltot = 0.f;

  const int nch = V10_NCH[i];
  const int base = V10_BASE[i];

  for (int c = 0; c < nch; ++c) {
    int slot = (base + c) * 16 + b;
    ltot += partML[slot * 128 + row];
    const uint4* po = reinterpret_cast<const uint4*>(
        partO + (size_t)slot * (128 * 128) + (size_t)row * 128 + c0);
    #pragma unroll
    for (int u = 0; u < 2; ++u) {
      uint4 v = po[u];
      acc[u*8+0] += bfbits2f(v.x << 16); acc[u*8+1] += bfbits2f(v.x & 0xffff0000u);
      acc[u*8+2] += bfbits2f(v.y << 16); acc[u*8+3] += bfbits2f(v.y & 0xffff0000u);
      acc[u*8+4] += bfbits2f(v.z << 16); acc[u*8+5] += bfbits2f(v.z & 0xffff0000u);
      acc[u*8+6] += bfbits2f(v.w << 16); acc[u*8+7] += bfbits2f(v.w & 0xffff0000u);
    }
  }
  float inv = 1.0f / ltot;
  float* orow = O + ((size_t)b * SS + 128 * i + row) * DD + c0;
  #pragma unroll
  for (int u = 0; u < 4; ++u) {
    float4 w;
    w.x = acc[4*u+0] * inv; w.y = acc[4*u+1] * inv;
    w.z = acc[4*u+2] * inv; w.w = acc[4*u+3] * inv;
    reinterpret_cast<float4*>(orow)[u] = w;
  }
}

// ---------------------------------------------------------------------------
// Emergency fallback (round-1 style, no ws) if workspace too small
// ---------------------------------------------------------------------------
__device__ __forceinline__ int sigma_col(int a) {
  return (a & 35) | ((a & 12) << 1) | ((a & 16) >> 2);
}

__global__ __launch_bounds__(256) void sdpa_naive(
    const float* __restrict__ Q, const float* __restrict__ K,
    const float* __restrict__ V, float* __restrict__ O)
{
  __shared__ __align__(16) char smem[64 * 128 * 2 * 2];
  char* Klds  = smem;
  char* Vtlds = smem + 64 * 128 * 2;

  const int b   = blockIdx.x;
  const int qb  = (int)gridDim.y - 1 - (int)blockIdx.y;
  const int q0  = qb * 64;
  const int tid = threadIdx.x;
  const int lane = tid & 63;
  const int wid  = tid >> 6;
  const int l15  = lane & 15;
  const int hi   = lane >> 4;

  const float* Qb = Q + (size_t)b * SS * DD;
  const float* Kb = K + (size_t)b * SS * DD;
  const float* Vb = V + (size_t)b * SS * DD;
  float*       Ob = O + (size_t)b * SS * DD;
  const float scale = 0.08838834764831845f;

  short8 qf[4];
  {
    const float* qrow = Qb + (size_t)(q0 + wid * 16 + l15) * DD;
    #pragma unroll
    for (int cc = 0; cc < 4; ++cc) {
      const float4* p = reinterpret_cast<const float4*>(qrow + 32 * cc + 8 * hi);
      float4 x = p[0], yv = p[1];
      short8 w;
      w[0]=f2bf(x.x*scale); w[1]=f2bf(x.y*scale); w[2]=f2bf(x.z*scale); w[3]=f2bf(x.w*scale);
      w[4]=f2bf(yv.x*scale); w[5]=f2bf(yv.y*scale); w[6]=f2bf(yv.z*scale); w[7]=f2bf(yv.w*scale);
      qf[cc] = w;
    }
  }

  f32x4 o[8];
  #pragma unroll
  for (int nt = 0; nt < 8; ++nt) o[nt] = (f32x4){0.f,0.f,0.f,0.f};
  float m = -INFINITY, lsum = 0.f;

  const int ntile = qb + 1;
  for (int t = 0; t < ntile; ++t) {
    const int kv0 = t * 64;
    if (t) __syncthreads();
    #pragma unroll
    for (int u = 0; u < 4; ++u) {
      int row = u * 16 + (tid >> 4);
      int col = 8 * (tid & 15);
      const float4* sp = reinterpret_cast<const float4*>(Kb + (size_t)(kv0 + row) * DD + col);
      float4 x = sp[0], yv = sp[1];
      short8 w;
      w[0]=f2bf(x.x); w[1]=f2bf(x.y); w[2]=f2bf(x.z); w[3]=f2bf(x.w);
      w[4]=f2bf(yv.x); w[5]=f2bf(yv.y); w[6]=f2bf(yv.z); w[7]=f2bf(yv.w);
      int off = (row * 256 + col * 2) ^ ((row & 7) << 4);
      *reinterpret_cast<short8*>(Klds + off) = w;
    }
    #pragma unroll
    for (int u = 0; u < 4; ++u) {
      int row = u * 16 + (tid >> 4);
      int col = 8 * (tid & 15);
      const float4* sp = reinterpret_cast<const float4*>(Vb + (size_t)(kv0 + row) * DD + col);
      float4 x = sp[0], yv = sp[1];
      int sc = sigma_col(row);
      float vals[8] = {x.x, x.y, x.z, x.w, yv.x, yv.y, yv.z, yv.w};
      #pragma unroll
      for (int j = 0; j < 8; ++j) {
        int d = col + j;
        int off = ((d << 7) + (sc << 1)) ^ ((((d >> 3) ^ d) & 7) << 4);
        *reinterpret_cast<unsigned short*>(Vtlds + off) = f2bf(vals[j]);
      }
    }
    __syncthreads();

    f32x4 sacc[4];
    #pragma unroll
    for (int g = 0; g < 4; ++g) {
      f32x4 acc = {0.f,0.f,0.f,0.f};
      #pragma unroll
      for (int cc = 0; cc < 4; ++cc) {
        int row = g * 16 + l15;
        int off = (row * 256 + (32 * cc + 8 * hi) * 2) ^ ((row & 7) << 4);
        short8 kf = *reinterpret_cast<const short8*>(Klds + off);
        acc = __builtin_amdgcn_mfma_f32_16x16x32_bf16(kf, qf[cc], acc, 0, 0, 0);
      }
      sacc[g] = acc;
    }
    if (t == ntile - 1) {
      const int q = q0 + wid * 16 + l15;
      #pragma unroll
      for (int g = 0; g < 4; ++g)
        #pragma unroll
        for (int ii = 0; ii < 4; ++ii) {
          int key = kv0 + g * 16 + 4 * hi + ii;
          if (key > q) sacc[g][ii] = -1e30f;
        }
    }
    float tmax = -INFINITY;
    #pragma unroll
    for (int g = 0; g < 4; ++g)
      #pragma unroll
      for (int ii = 0; ii < 4; ++ii) tmax = fmaxf(tmax, sacc[g][ii]);
    tmax = fmaxf(tmax, __shfl_xor(tmax, 16));
    tmax = fmaxf(tmax, __shfl_xor(tmax, 32));
    float mnew = fmaxf(m, tmax);
    float corr = __expf(m - mnew);
    m = mnew;
    float p[4][4]; float psum = 0.f;
    #pragma unroll
    for (int g = 0; g < 4; ++g)
      #pragma unroll
      for (int ii = 0; ii < 4; ++ii) {
        float pv = __expf(sacc[g][ii] - mnew);
        p[g][ii] = pv; psum += pv;
      }
    psum += __shfl_xor(psum, 16);
    psum += __shfl_xor(psum, 32);
    lsum = lsum * corr + psum;
    float corrO[4];
    #pragma unroll
    for (int ii = 0; ii < 4; ++ii) corrO[ii] = __shfl(corr, 4 * hi + ii);
    #pragma unroll
    for (int nt = 0; nt < 8; ++nt)
      #pragma unroll
      for (int ii = 0; ii < 4; ++ii) o[nt][ii] *= corrO[ii];
    short8 pfr[2];
    #pragma unroll
    for (int ks = 0; ks < 2; ++ks) {
      short8 w;
      #pragma unroll
      for (int ii = 0; ii < 4; ++ii) { w[ii] = f2bf(p[2*ks][ii]); w[4+ii] = f2bf(p[2*ks+1][ii]); }
      pfr[ks] = w;
    }
    #pragma unroll
    for (int ks = 0; ks < 2; ++ks)
      #pragma unroll
      for (int nt = 0; nt < 8; ++nt) {
        int d = nt * 16 + l15;
        int off = ((d << 7) + (ks * 32 + 8 * hi) * 2) ^ ((((d >> 3) ^ d) & 7) << 4);
        short8 vvf = *reinterpret_cast<const short8*>(Vtlds + off);
        o[nt] = __builtin_amdgcn_mfma_f32_16x16x32_bf16(pfr[ks], vvf, o[nt], 0, 0, 0);
      }
  }
  float rl = 1.0f / lsum;
  float rlO[4];
  #pragma unroll
  for (int ii = 0; ii < 4; ++ii) rlO[ii] = __shfl(rl, 4 * hi + ii);
  const int qrow = q0 + wid * 16;
  #pragma unroll
  for (int nt = 0; nt < 8; ++nt)
    #pragma unroll
    for (int ii = 0; ii < 4; ++ii)
      Ob[(size_t)(qrow + 4 * hi + ii) * DD + nt * 16 + l15] = o[nt][ii] * rlO[ii];
}

extern "C" void kernel_launch(void* const* d_in, const int* in_sizes, int n_in,
                              void* d_out, int out_size, void* d_ws, size_t ws_size,
                              hipStream_t stream) {
  const float* Q = (const float*)d_in[0];
  const float* K = (const float*)d_in[1];
  const float* V = (const float*)d_in[2];
  float* O = (float*)d_out;
  char* ws = (char*)d_ws;

  if (ws_size >= WS_NEED) {
    unsigned short* partO = (unsigned short*)(ws + WS_PO);
    float* partML = (float*)(ws + WS_ML);
    prepack_kv10<<<dim3(16, NKT), 256, 0, stream>>>(K, V, ws);
    sdpa_v10<<<dim3(NBLK), 256, 0, stream>>>(Q, ws, O, partO, partML);
    merge_v10<<<dim3(16, 12, 4), 256, 0, stream>>>(partO, partML, O);
  } else {
    sdpa_naive<<<dim3(16, 32), 256, 0, stream>>>(Q, K, V, O);
  }
}

// Round 11
// 63.184 us; speedup vs baseline: 1.5178x; 1.5178x over previous
//
#include <hip/hip_runtime.h>
#include <hip/hip_bf16.h>
#include <cstdint>

#define SS   2048
#define DD   128
#define KBLK 64
#define NKT  32                      // 64-key tiles per batch
#define TILE_BYTES 16384             // 64 keys x 128 d bf16, frag-ordered

#define NBLK11 320                   // 8-wave blocks, QBLK=256, chunks of <=4 periods
#define WS_K    ((size_t)0)
#define WS_V    ((size_t)16 * NKT * TILE_BYTES)             // 8 MB
#define WS_PO   ((size_t)16 * NKT * TILE_BYTES * 2)         // 16 MB
#define WS_ML   (WS_PO + (size_t)NBLK11 * 256 * 128 * 2)    // +21 MB
#define WS_NEED (WS_ML + (size_t)NBLK11 * 256 * 4)          // ~37.3 MB

typedef __attribute__((ext_vector_type(8)))  short short8;   // 8 bf16 (MFMA A/B)
typedef __attribute__((ext_vector_type(16))) float f32x16;   // 32x32 MFMA C/D
typedef __attribute__((ext_vector_type(4)))  float f32x4;

__device__ __forceinline__ unsigned short f2bf(float x) {
  return __builtin_bit_cast(unsigned short, (__bf16)x);
}
__device__ __forceinline__ float bfbits2f(unsigned int lo16shifted) {
  return __builtin_bit_cast(float, lo16shifted);
}

// ---- v11 chunk tables: q-block i (256 rows) has 2i+2 PERIODS (128 keys each);
// chunks of <=4 periods. 20 slots/batch -> 320 blocks.
__device__ __constant__ unsigned char V11_I[20]    = {0,1,2,2,3,3,4,4,4,5,5,5,6,6,6,6,7,7,7,7};
__device__ __constant__ unsigned char V11_BASE[8]  = {0,1,2,4,6,9,12,16};
__device__ __constant__ unsigned char V11_NCH[8]   = {1,1,2,2,3,3,4,4};

// ---------------------------------------------------------------------------
// Pre-pass: FRAGMENT-ORDERED bf16 tiles (proven v8-v10 layout, per 64-key tile)
//   K tile entry e = g*512 + s*64 + lane, 16B = K[g*32+l31][s*16+h*8 ..]
//   V tile entry e = (dg*4+s4)*64 + lane, 16B = V^T[dg*32+l31][pi-slots]
// ---------------------------------------------------------------------------
__global__ __launch_bounds__(256) void prepack_kv11(
    const float* __restrict__ K, const float* __restrict__ V, char* __restrict__ ws)
{
  __shared__ float st[64][132];
  const int b = blockIdx.x, t = blockIdx.y;
  const int tid = threadIdx.x;
  const float* Kt = K + ((size_t)b * SS + t * KBLK) * DD;
  const float* Vt = V + ((size_t)b * SS + t * KBLK) * DD;
  char* Kd = ws + WS_K + ((size_t)(b * NKT + t)) * TILE_BYTES;
  char* Vd = ws + WS_V + ((size_t)(b * NKT + t)) * TILE_BYTES;

  #pragma unroll
  for (int u = 0; u < 4; ++u) {
    int row = u * 16 + (tid >> 4);
    int col = 8 * (tid & 15);
    const float4* sp = reinterpret_cast<const float4*>(Kt + (size_t)row * DD + col);
    float4 x = sp[0], y = sp[1];
    *reinterpret_cast<float4*>(&st[row][col])     = x;
    *reinterpret_cast<float4*>(&st[row][col + 4]) = y;
  }
  __syncthreads();
  #pragma unroll
  for (int u = 0; u < 4; ++u) {
    int e = u * 256 + tid;
    int g = e >> 9, s = (e >> 6) & 7, lane = e & 63;
    int h = lane >> 5, l31 = lane & 31;
    int key = g * 32 + l31;
    int d0 = s * 16 + h * 8;
    float4 x = *reinterpret_cast<const float4*>(&st[key][d0]);
    float4 y = *reinterpret_cast<const float4*>(&st[key][d0 + 4]);
    short8 w;
    w[0] = f2bf(x.x); w[1] = f2bf(x.y); w[2] = f2bf(x.z); w[3] = f2bf(x.w);
    w[4] = f2bf(y.x); w[5] = f2bf(y.y); w[6] = f2bf(y.z); w[7] = f2bf(y.w);
    *reinterpret_cast<short8*>(Kd + e * 16) = w;
  }
  __syncthreads();

  #pragma unroll
  for (int u = 0; u < 4; ++u) {
    int row = u * 16 + (tid >> 4);
    int col = 8 * (tid & 15);
    const float4* sp = reinterpret_cast<const float4*>(Vt + (size_t)row * DD + col);
    float4 x = sp[0], y = sp[1];
    *reinterpret_cast<float4*>(&st[row][col])     = x;
    *reinterpret_cast<float4*>(&st[row][col + 4]) = y;
  }
  __syncthreads();
  #pragma unroll
  for (int u = 0; u < 4; ++u) {
    int e = u * 256 + tid;
    int dg = e >> 8, s4 = (e >> 6) & 3, lane = e & 63;
    int h = lane >> 5, l31 = lane & 31;
    int d = dg * 32 + l31;
    int y8 = s4 * 2 + h;
    short8 w;
    #pragma unroll
    for (int j = 0; j < 8; ++j) {
      int a = ((y8 >> 2) << 5) | (((y8 >> 1) & 1) << 4) | ((j >> 2) << 3) | (j & 3) | ((y8 & 1) << 2);
      w[j] = f2bf(st[a][d]);
    }
    *reinterpret_cast<short8*>(Vd + e * 16) = w;
  }
}

// ---------------------------------------------------------------------------
// Main v11: 8 waves (512 thr), QBLK=256, 128-key periods (two frag tiles),
// double-buffered 128KB LDS, global_load_lds staging (R4-proven schedule:
// issue next period's loads BEFORE compute, one __syncthreads per period).
// ---------------------------------------------------------------------------
__device__ __forceinline__ void stage_pair(const char* Kws, const char* Vws, int p,
                                           char* Kl, char* Vl, int wid, int lane)
{
  const char* Ksrc = Kws + (size_t)(2 * p) * TILE_BYTES;   // 32KB contiguous
  const char* Vsrc = Vws + (size_t)(2 * p) * TILE_BYTES;
  #pragma unroll
  for (int j = 0; j < 4; ++j) {
    int off = j * 8192 + wid * 1024;   // wave-uniform LDS base; HW adds lane*16
    __builtin_amdgcn_global_load_lds(
        (const __attribute__((address_space(1))) unsigned int*)(Ksrc + off + lane * 16),
        (__attribute__((address_space(3))) unsigned int*)(Kl + off), 16, 0, 0);
  }
  #pragma unroll
  for (int j = 0; j < 4; ++j) {
    int off = j * 8192 + wid * 1024;
    __builtin_amdgcn_global_load_lds(
        (const __attribute__((address_space(1))) unsigned int*)(Vsrc + off + lane * 16),
        (__attribute__((address_space(3))) unsigned int*)(Vl + off), 16, 0, 0);
  }
}

__global__ __launch_bounds__(512) void sdpa_v11(
    const float* __restrict__ Q, const char* __restrict__ ws,
    float* __restrict__ O, unsigned short* __restrict__ partO,
    float* __restrict__ partML)
{
  __shared__ __align__(16) char smem[2 * 65536];   // [buf][K 32KB | V 32KB]

  const int y = blockIdx.x;
  const int b = y & 15;
  const int slot = y >> 4;
  const int i = V11_I[slot];
  const int c = slot - V11_BASE[i];
  const int nch = V11_NCH[i];
  const int periods = 2 * i + 2;
  const int p0 = 4 * c;
  const int ntile = (periods - p0 < 4) ? (periods - p0) : 4;
  const bool dostore = (nch == 1);

  const int tid  = threadIdx.x;
  const int lane = tid & 63;
  const int wid  = tid >> 6;     // 0..7
  const int l31  = lane & 31;
  const int h    = lane >> 5;

  const float* Qb  = Q + (size_t)b * SS * DD;
  const char*  Kws = ws + WS_K + ((size_t)(b * NKT)) * TILE_BYTES;
  const char*  Vws = ws + WS_V + ((size_t)(b * NKT)) * TILE_BYTES;

  const float qscale = 0.08838834764831845f * 1.4426950408889634f; // 1/sqrt(128)*log2e
  const int qg = 256 * i + wid * 32 + l31;

  // ---- Q fragments (B-operand), scale folded ----
  short8 qf[8];
  {
    const float* qrow = Qb + (size_t)qg * DD;
    #pragma unroll
    for (int s = 0; s < 8; ++s) {
      const float4* p = reinterpret_cast<const float4*>(qrow + s * 16 + h * 8);
      float4 x = p[0], z = p[1];
      short8 w;
      w[0] = f2bf(x.x * qscale); w[1] = f2bf(x.y * qscale);
      w[2] = f2bf(x.z * qscale); w[3] = f2bf(x.w * qscale);
      w[4] = f2bf(z.x * qscale); w[5] = f2bf(z.y * qscale);
      w[6] = f2bf(z.z * qscale); w[7] = f2bf(z.w * qscale);
      qf[s] = w;
    }
  }

  f32x16 o[4];
  #pragma unroll
  for (int dg = 0; dg < 4; ++dg)
    #pragma unroll
    for (int r = 0; r < 16; ++r) o[dg][r] = 0.f;
  float lsum = 0.f;

  int cur = 0;
  stage_pair(Kws, Vws, p0, smem, smem + 32768, wid, lane);
  __syncthreads();

  for (int t = 0; t < ntile; ++t) {
    const int p = p0 + t;
    // issue next period's loads BEFORE compute (latency hides under compute)
    if (t + 1 < ntile) {
      char* nb = smem + (cur ^ 1) * 65536;
      stage_pair(Kws, Vws, p + 1, nb, nb + 32768, wid, lane);
    }
    const char* Kl = smem + cur * 65536;
    const char* Vl = Kl + 32768;
    const bool domask = (p >= 2 * i);

    short8 pf[8];
    float psum = 0.f;

    // ---- QK^T: 4 groups of 32 keys (two frag tiles in LDS) ----
    #pragma unroll
    for (int g = 0; g < 4; ++g) {
      const char* Kg = Kl + (g >> 1) * 16384 + (g & 1) * 8192;
      short8 kf[8];
      #pragma unroll
      for (int s = 0; s < 8; ++s)
        kf[s] = *reinterpret_cast<const short8*>(Kg + s * 1024 + lane * 16);

      f32x16 acc;
      #pragma unroll
      for (int r = 0; r < 16; ++r) acc[r] = 0.f;
      __builtin_amdgcn_s_setprio(1);
      #pragma unroll
      for (int s = 0; s < 8; ++s)
        acc = __builtin_amdgcn_mfma_f32_32x32x16_bf16(kf[s], qf[s], acc, 0, 0, 0);
      __builtin_amdgcn_s_setprio(0);

      if (domask) {
        const int kb = p * 128 + g * 32 + 4 * h;
        #pragma unroll
        for (int r = 0; r < 16; ++r) {
          int keyg = kb + (r & 3) + 8 * (r >> 2);
          if (keyg > qg) acc[r] = -1e30f;
        }
      }

      float pg[16];
      #pragma unroll
      for (int r = 0; r < 16; ++r) pg[r] = exp2f(acc[r]);
      float s0 = ((pg[0]+pg[1])+(pg[2]+pg[3])) + ((pg[4]+pg[5])+(pg[6]+pg[7]));
      float s1 = ((pg[8]+pg[9])+(pg[10]+pg[11])) + ((pg[12]+pg[13])+(pg[14]+pg[15]));
      psum += s0 + s1;

      short8 w0, w1;
      #pragma unroll
      for (int j = 0; j < 8; ++j) { w0[j] = f2bf(pg[j]); w1[j] = f2bf(pg[8 + j]); }
      pf[2 * g]     = w0;
      pf[2 * g + 1] = w1;
    }
    lsum += psum;

    // ---- PV: o[dg] += sum over 8 slot-groups (2 tiles x 4) ----
    __builtin_amdgcn_s_setprio(1);
    #pragma unroll
    for (int dg = 0; dg < 4; ++dg) {
      #pragma unroll
      for (int s8 = 0; s8 < 8; ++s8) {
        const char* Vg = Vl + (s8 >> 2) * 16384 + (dg * 4 + (s8 & 3)) * 1024;
        short8 vf8 = *reinterpret_cast<const short8*>(Vg + lane * 16);
        o[dg] = __builtin_amdgcn_mfma_f32_32x32x16_bf16(vf8, pf[s8], o[dg], 0, 0, 0);
      }
    }
    __builtin_amdgcn_s_setprio(0);

    if (t + 1 < ntile) {
      __syncthreads();   // drains own loads (flew during compute); orders buffers
      cur ^= 1;
    }
  }

  // ---- epilogue ----
  lsum += __shfl_xor(lsum, 32);

  if (dostore) {
    float inv = 1.0f / lsum;
    float* Ob = O + (size_t)b * SS * DD + (size_t)qg * DD;
    #pragma unroll
    for (int dg = 0; dg < 4; ++dg)
      #pragma unroll
      for (int rq = 0; rq < 4; ++rq) {
        int d0 = dg * 32 + 8 * rq + 4 * h;
        float4 w;
        w.x = o[dg][4 * rq + 0] * inv;
        w.y = o[dg][4 * rq + 1] * inv;
        w.z = o[dg][4 * rq + 2] * inv;
        w.w = o[dg][4 * rq + 3] * inv;
        *reinterpret_cast<float4*>(Ob + d0) = w;
      }
  } else {
    unsigned short* po = partO + (size_t)y * (256 * 128) + (size_t)(wid * 32 + l31) * 128;
    #pragma unroll
    for (int dg = 0; dg < 4; ++dg)
      #pragma unroll
      for (int rq = 0; rq < 4; ++rq) {
        int d0 = dg * 32 + 8 * rq + 4 * h;
        ushort4 u;
        u.x = f2bf(o[dg][4 * rq + 0]);
        u.y = f2bf(o[dg][4 * rq + 1]);
        u.z = f2bf(o[dg][4 * rq + 2]);
        u.w = f2bf(o[dg][4 * rq + 3]);
        *reinterpret_cast<ushort4*>(po + d0) = u;
      }
    if (h == 0) partML[y * 256 + wid * 32 + l31] = lsum;
  }
}

// ---------------------------------------------------------------------------
// Merge for i>=2: O[b][256i+row][:] = (sum_c U_c) / (sum_c l_c)
// grid (16 batches, 6 qblocks, 8 rowgroups) x 256 thr
// ---------------------------------------------------------------------------
__global__ __launch_bounds__(256) void merge_v11(
    const unsigned short* __restrict__ partO, const float* __restrict__ partML,
    float* __restrict__ O)
{
  const int b = blockIdx.x;
  const int i = blockIdx.y + 2;
  const int rg = blockIdx.z;
  const int tid = threadIdx.x;
  const int row = rg * 32 + (tid >> 3);      // 0..255
  const int c0  = (tid & 7) * 16;

  float acc[16];
  #pragma unroll
  for (int u = 0; u < 16; ++u) acc[u] = 0.f;
  float ltot = 0.f;

  const int nch = V11_NCH[i];
  const int base = V11_BASE[i];

  for (int c = 0; c < nch; ++c) {
    int slot = (base + c) * 16 + b;
    ltot += partML[slot * 256 + row];
    const uint4* po = reinterpret_cast<const uint4*>(
        partO + (size_t)slot * (256 * 128) + (size_t)row * 128 + c0);
    #pragma unroll
    for (int u = 0; u < 2; ++u) {
      uint4 v = po[u];
      acc[u*8+0] += bfbits2f(v.x << 16); acc[u*8+1] += bfbits2f(v.x & 0xffff0000u);
      acc[u*8+2] += bfbits2f(v.y << 16); acc[u*8+3] += bfbits2f(v.y & 0xffff0000u);
      acc[u*8+4] += bfbits2f(v.z << 16); acc[u*8+5] += bfbits2f(v.z & 0xffff0000u);
      acc[u*8+6] += bfbits2f(v.w << 16); acc[u*8+7] += bfbits2f(v.w & 0xffff0000u);
    }
  }
  float inv = 1.0f / ltot;
  float* orow = O + ((size_t)b * SS + 256 * i + row) * DD + c0;
  #pragma unroll
  for (int u = 0; u < 4; ++u) {
    float4 w;
    w.x = acc[4*u+0] * inv; w.y = acc[4*u+1] * inv;
    w.z = acc[4*u+2] * inv; w.w = acc[4*u+3] * inv;
    reinterpret_cast<float4*>(orow)[u] = w;
  }
}

// ---------------------------------------------------------------------------
// Emergency fallback (round-1 style, no ws) if workspace too small
// ---------------------------------------------------------------------------
__device__ __forceinline__ int sigma_col(int a) {
  return (a & 35) | ((a & 12) << 1) | ((a & 16) >> 2);
}

__global__ __launch_bounds__(256) void sdpa_naive(
    const float* __restrict__ Q, const float* __restrict__ K,
    const float* __restrict__ V, float* __restrict__ O)
{
  __shared__ __align__(16) char smem[64 * 128 * 2 * 2];
  char* Klds  = smem;
  char* Vtlds = smem + 64 * 128 * 2;

  const int b   = blockIdx.x;
  const int qb  = (int)gridDim.y - 1 - (int)blockIdx.y;
  const int q0  = qb * 64;
  const int tid = threadIdx.x;
  const int lane = tid & 63;
  const int wid  = tid >> 6;
  const int l15  = lane & 15;
  const int hi   = lane >> 4;

  const float* Qb = Q + (size_t)b * SS * DD;
  const float* Kb = K + (size_t)b * SS * DD;
  const float* Vb = V + (size_t)b * SS * DD;
  float*       Ob = O + (size_t)b * SS * DD;
  const float scale = 0.08838834764831845f;

  short8 qf[4];
  {
    const float* qrow = Qb + (size_t)(q0 + wid * 16 + l15) * DD;
    #pragma unroll
    for (int cc = 0; cc < 4; ++cc) {
      const float4* p = reinterpret_cast<const float4*>(qrow + 32 * cc + 8 * hi);
      float4 x = p[0], yv = p[1];
      short8 w;
      w[0]=f2bf(x.x*scale); w[1]=f2bf(x.y*scale); w[2]=f2bf(x.z*scale); w[3]=f2bf(x.w*scale);
      w[4]=f2bf(yv.x*scale); w[5]=f2bf(yv.y*scale); w[6]=f2bf(yv.z*scale); w[7]=f2bf(yv.w*scale);
      qf[cc] = w;
    }
  }

  f32x4 o[8];
  #pragma unroll
  for (int nt = 0; nt < 8; ++nt) o[nt] = (f32x4){0.f,0.f,0.f,0.f};
  float m = -INFINITY, lsum = 0.f;

  const int ntile = qb + 1;
  for (int t = 0; t < ntile; ++t) {
    const int kv0 = t * 64;
    if (t) __syncthreads();
    #pragma unroll
    for (int u = 0; u < 4; ++u) {
      int row = u * 16 + (tid >> 4);
      int col = 8 * (tid & 15);
      const float4* sp = reinterpret_cast<const float4*>(Kb + (size_t)(kv0 + row) * DD + col);
      float4 x = sp[0], yv = sp[1];
      short8 w;
      w[0]=f2bf(x.x); w[1]=f2bf(x.y); w[2]=f2bf(x.z); w[3]=f2bf(x.w);
      w[4]=f2bf(yv.x); w[5]=f2bf(yv.y); w[6]=f2bf(yv.z); w[7]=f2bf(yv.w);
      int off = (row * 256 + col * 2) ^ ((row & 7) << 4);
      *reinterpret_cast<short8*>(Klds + off) = w;
    }
    #pragma unroll
    for (int u = 0; u < 4; ++u) {
      int row = u * 16 + (tid >> 4);
      int col = 8 * (tid & 15);
      const float4* sp = reinterpret_cast<const float4*>(Vb + (size_t)(kv0 + row) * DD + col);
      float4 x = sp[0], yv = sp[1];
      int sc = sigma_col(row);
      float vals[8] = {x.x, x.y, x.z, x.w, yv.x, yv.y, yv.z, yv.w};
      #pragma unroll
      for (int j = 0; j < 8; ++j) {
        int d = col + j;
        int off = ((d << 7) + (sc << 1)) ^ ((((d >> 3) ^ d) & 7) << 4);
        *reinterpret_cast<unsigned short*>(Vtlds + off) = f2bf(vals[j]);
      }
    }
    __syncthreads();

    f32x4 sacc[4];
    #pragma unroll
    for (int g = 0; g < 4; ++g) {
      f32x4 acc = {0.f,0.f,0.f,0.f};
      #pragma unroll
      for (int cc = 0; cc < 4; ++cc) {
        int row = g * 16 + l15;
        int off = (row * 256 + (32 * cc + 8 * hi) * 2) ^ ((row & 7) << 4);
        short8 kf = *reinterpret_cast<const short8*>(Klds + off);
        acc = __builtin_amdgcn_mfma_f32_16x16x32_bf16(kf, qf[cc], acc, 0, 0, 0);
      }
      sacc[g] = acc;
    }
    if (t == ntile - 1) {
      const int q = q0 + wid * 16 + l15;
      #pragma unroll
      for (int g = 0; g < 4; ++g)
        #pragma unroll
        for (int ii = 0; ii < 4; ++ii) {
          int key = kv0 + g * 16 + 4 * hi + ii;
          if (key > q) sacc[g][ii] = -1e30f;
        }
    }
    float tmax = -INFINITY;
    #pragma unroll
    for (int g = 0; g < 4; ++g)
      #pragma unroll
      for (int ii = 0; ii < 4; ++ii) tmax = fmaxf(tmax, sacc[g][ii]);
    tmax = fmaxf(tmax, __shfl_xor(tmax, 16));
    tmax = fmaxf(tmax, __shfl_xor(tmax, 32));
    float mnew = fmaxf(m, tmax);
    float corr = __expf(m - mnew);
    m = mnew;
    float p[4][4]; float psum = 0.f;
    #pragma unroll
    for (int g = 0; g < 4; ++g)
      #pragma unroll
      for (int ii = 0; ii < 4; ++ii) {
        float pv = __expf(sacc[g][ii] - mnew);
        p[g][ii] = pv; psum += pv;
      }
    psum += __shfl_xor(psum, 16);
    psum += __shfl_xor(psum, 32);
    lsum = lsum * corr + psum;
    float corrO[4];
    #pragma unroll
    for (int ii = 0; ii < 4; ++ii) corrO[ii] = __shfl(corr, 4 * hi + ii);
    #pragma unroll
    for (int nt = 0; nt < 8; ++nt)
      #pragma unroll
      for (int ii = 0; ii < 4; ++ii) o[nt][ii] *= corrO[ii];
    short8 pfr[2];
    #pragma unroll
    for (int ks = 0; ks < 2; ++ks) {
      short8 w;
      #pragma unroll
      for (int ii = 0; ii < 4; ++ii) { w[ii] = f2bf(p[2*ks][ii]); w[4+ii] = f2bf(p[2*ks+1][ii]); }
      pfr[ks] = w;
    }
    #pragma unroll
    for (int ks = 0; ks < 2; ++ks)
      #pragma unroll
      for (int nt = 0; nt < 8; ++nt) {
        int d = nt * 16 + l15;
        int off = ((d << 7) + (ks * 32 + 8 * hi) * 2) ^ ((((d >> 3) ^ d) & 7) << 4);
        short8 vvf = *reinterpret_cast<const short8*>(Vtlds + off);
        o[nt] = __builtin_amdgcn_mfma_f32_16x16x32_bf16(pfr[ks], vvf, o[nt], 0, 0, 0);
      }
  }
  float rl = 1.0f / lsum;
  float rlO[4];
  #pragma unroll
  for (int ii = 0; ii < 4; ++ii) rlO[ii] = __shfl(rl, 4 * hi + ii);
  const int qrow = q0 + wid * 16;
  #pragma unroll
  for (int nt = 0; nt < 8; ++nt)
    #pragma unroll
    for (int ii = 0; ii < 4; ++ii)
      Ob[(size_t)(qrow + 4 * hi + ii) * DD + nt * 16 + l15] = o[nt][ii] * rlO[ii];
}

extern "C" void kernel_launch(void* const* d_in, const int* in_sizes, int n_in,
                              void* d_out, int out_size, void* d_ws, size_t ws_size,
                              hipStream_t stream) {
  const float* Q = (const float*)d_in[0];
  const float* K = (const float*)d_in[1];
  const float* V = (const float*)d_in[2];
  float* O = (float*)d_out;
  char* ws = (char*)d_ws;

  if (ws_size >= WS_NEED) {
    unsigned short* partO = (unsigned short*)(ws + WS_PO);
    float* partML = (float*)(ws + WS_ML);
    prepack_kv11<<<dim3(16, NKT), 256, 0, stream>>>(K, V, ws);
    sdpa_v11<<<dim3(NBLK11), 512, 0, stream>>>(Q, ws, O, partO, partML);
    merge_v11<<<dim3(16, 6, 8), 256, 0, stream>>>(partO, partML, O);
  } else {
    sdpa_naive<<<dim3(16, 32), 256, 0, stream>>>(Q, K, V, O);
  }
}